// Round 1
// baseline (431.707 us; speedup 1.0000x reference)
//
#include <hip/hip_runtime.h>

// Problem constants (fixed by setup_inputs):
//   features: (V=8, F=16, C=1024, H=14, W=14) f32  -> VF = 128
//   boxes:    (N=768, 4) f32
//   frame_idx:(N=768,)  i32
// Outputs concatenated in d_out (f32):
//   roi_feats [768,1024,7,7]  = 38,535,168
//   s_node    [8,16,1024]     =    131,072
//   fake_h_s  [8,16,1024,12,12]= 18,874,368
constexpr int VF = 128;
constexpr int C  = 1024;
constexpr int H  = 14;
constexpr int W  = 14;
constexpr int HW = H * W;          // 196
constexpr int NBOX = 768;
constexpr int OUTSZ = 7;
constexpr float SCALE = 1.0f / 16.0f;

constexpr long long ROI_ELEMS  = (long long)NBOX * C * OUTSZ * OUTSZ;  // 38535168
constexpr long long SNODE_ELEMS = (long long)VF * C;                   // 131072

// One wave (64 lanes) per (box, channel) task.
// Lane g = gy*8+gx computes bilinear sample val[gy][gx] of the 8x8 grid,
// then pooled(i,j) = 0.25*(val[i][j]+val[i+1][j]+val[i][j+1]+val[i+1][j+1])
// via cross-lane shuffles; lanes with gy<7 && gx<7 write out.
__global__ void roi_kernel(const float* __restrict__ feat,
                           const float* __restrict__ boxes,
                           const int* __restrict__ fidx,
                           float* __restrict__ out) {
    const int lane  = threadIdx.x & 63;
    const int wave  = (blockIdx.x * blockDim.x + threadIdx.x) >> 6;
    const int nwav  = (gridDim.x * blockDim.x) >> 6;
    const int total = NBOX * C;

    const int gy = lane >> 3;
    const int gx = lane & 7;
    const float tx = (float)gx * (1.0f / 7.0f);
    const float ty = (float)gy * (1.0f / 7.0f);

    for (int task = wave; task < total; task += nwav) {
        const int n = task >> 10;      // /1024
        const int c = task & 1023;

        const float bx1 = boxes[n * 4 + 0] * SCALE;
        const float by1 = boxes[n * 4 + 1] * SCALE;
        const float bx2 = boxes[n * 4 + 2] * SCALE;
        const float by2 = boxes[n * 4 + 3] * SCALE;
        const int b = fidx[n];

        const float* f = feat + ((size_t)b * C + c) * HW;

        float xs = bx1 + tx * (bx2 - bx1);
        float ys = by1 + ty * (by2 - by1);
        xs = fminf(fmaxf(xs, 0.0f), (float)(W - 1));
        ys = fminf(fmaxf(ys, 0.0f), (float)(H - 1));

        const int x0 = (int)floorf(xs);
        const int y0 = (int)floorf(ys);
        const int x1 = min(x0 + 1, W - 1);
        const int y1 = min(y0 + 1, H - 1);
        const float wx = xs - (float)x0;
        const float wy = ys - (float)y0;

        const float f00 = f[y0 * W + x0];
        const float f01 = f[y0 * W + x1];
        const float f10 = f[y1 * W + x0];
        const float f11 = f[y1 * W + x1];

        const float top = f00 + wx * (f01 - f00);
        const float bot = f10 + wx * (f11 - f10);
        const float val = top + wy * (bot - top);

        // pooling neighbors via cross-lane shuffle (all lanes participate)
        const float v_r  = __shfl(val, lane + 1, 64);
        const float v_d  = __shfl(val, lane + 8, 64);
        const float v_dr = __shfl(val, lane + 9, 64);

        if (gy < OUTSZ && gx < OUTSZ) {
            const float p = 0.25f * (val + v_r + v_d + v_dr);
            out[(((size_t)n * C + c) * OUTSZ + gy) * OUTSZ + gx] = p;
        }
    }
}

// One wave per (vf, c): mean over 196 floats -> s_node; inner 12x12 crop -> fake_h_s.
__global__ void tail_kernel(const float* __restrict__ feat,
                            float* __restrict__ s_node,
                            float* __restrict__ fake) {
    const int lane  = threadIdx.x & 63;
    const int wave  = (blockIdx.x * blockDim.x + threadIdx.x) >> 6;
    const int nwav  = (gridDim.x * blockDim.x) >> 6;
    const int total = VF * C;   // 131072

    for (int task = wave; task < total; task += nwav) {
        const float* f = feat + (size_t)task * HW;

        // ---- mean of 196 contiguous floats ----
        float s = f[lane] + f[lane + 64] + f[lane + 128];
        if (lane < 4) s += f[lane + 192];
        #pragma unroll
        for (int off = 32; off; off >>= 1) s += __shfl_down(s, off, 64);
        if (lane == 0) s_node[task] = s * (1.0f / 196.0f);

        // ---- inner crop [1:13,1:13] -> 144 floats (re-reads hit L1) ----
        float* o = fake + (size_t)task * 144;
        {
            int oi = lane;
            int yy = oi / 12, xx = oi - yy * 12;
            o[oi] = f[(yy + 1) * W + xx + 1];
        }
        {
            int oi = lane + 64;
            int yy = oi / 12, xx = oi - yy * 12;
            o[oi] = f[(yy + 1) * W + xx + 1];
        }
        if (lane < 16) {
            int oi = lane + 128;
            int yy = oi / 12, xx = oi - yy * 12;
            o[oi] = f[(yy + 1) * W + xx + 1];
        }
    }
}

extern "C" void kernel_launch(void* const* d_in, const int* in_sizes, int n_in,
                              void* d_out, int out_size, void* d_ws, size_t ws_size,
                              hipStream_t stream) {
    const float* feat  = (const float*)d_in[0];
    const float* boxes = (const float*)d_in[1];
    const int*   fidx  = (const int*)d_in[2];

    float* roi    = (float*)d_out;
    float* s_node = roi + ROI_ELEMS;
    float* fake   = s_node + SNODE_ELEMS;

    // roi: 768*1024 = 786432 wave-tasks; 2048 blocks x 256 thr = 8192 waves
    roi_kernel<<<2048, 256, 0, stream>>>(feat, boxes, fidx, roi);
    // tail: 131072 wave-tasks
    tail_kernel<<<2048, 256, 0, stream>>>(feat, s_node, fake);
}

// Round 2
// 366.149 us; speedup vs baseline: 1.1790x; 1.1790x over previous
//
#include <hip/hip_runtime.h>

// features: (V=8, F=16, C=1024, H=14, W=14) f32 -> VF=128 frames
// boxes:    (N=768, 4) f32 ; frame_idx: (N=768,) i32
// Outputs (f32, concatenated):
//   roi_feats [768,1024,7,7], s_node [8,16,1024], fake_h_s [8,16,1024,12,12]
constexpr int VF = 128;
constexpr int C  = 1024;
constexpr int H  = 14;
constexpr int W  = 14;
constexpr int HW = H * W;              // 196
constexpr int NBOX = 768;
constexpr int OUTSZ = 7;
constexpr float SCALE = 1.0f / 16.0f;

constexpr long long ROI_ELEMS   = (long long)NBOX * C * OUTSZ * OUTSZ;
constexpr long long SNODE_ELEMS = (long long)VF * C;

constexpr int ROI_CHUNKS   = 16;                    // channel chunks per box
constexpr int CH_PER_CHUNK = C / ROI_CHUNKS;        // 64
constexpr int ROI_WAVES    = NBOX * ROI_CHUNKS;     // 12288
constexpr int TAIL_WAVES   = 4096;
constexpr int TOTAL_WAVES  = ROI_WAVES + TAIL_WAVES; // 16384
constexpr int TAIL_TASKS   = VF * C;                // 131072

__global__ __launch_bounds__(256) void fused_kernel(
    const float* __restrict__ feat,
    const float* __restrict__ boxes,
    const int*   __restrict__ fidx,
    float* __restrict__ roi,
    float* __restrict__ s_node,
    float* __restrict__ fake)
{
    const int lane = threadIdx.x & 63;
    const int w    = (blockIdx.x * blockDim.x + threadIdx.x) >> 6;

    if (w < ROI_WAVES) {
        // ---------------- RoIAlign path: wave = (box n, 64-channel chunk) ----
        const int n     = w >> 4;
        const int chunk = w & 15;

        const float bx1 = boxes[n * 4 + 0] * SCALE;
        const float by1 = boxes[n * 4 + 1] * SCALE;
        const float bx2 = boxes[n * 4 + 2] * SCALE;
        const float by2 = boxes[n * 4 + 3] * SCALE;
        const int   b   = fidx[n];

        const int gy = lane >> 3;
        const int gx = lane & 7;

        // geometry: computed ONCE per wave, reused for 64 channels
        float xs = bx1 + ((float)gx * (1.0f / 7.0f)) * (bx2 - bx1);
        float ys = by1 + ((float)gy * (1.0f / 7.0f)) * (by2 - by1);
        xs = fminf(fmaxf(xs, 0.0f), (float)(W - 1));
        ys = fminf(fmaxf(ys, 0.0f), (float)(H - 1));
        const int x0 = (int)floorf(xs);
        const int y0 = (int)floorf(ys);
        const int x1 = min(x0 + 1, W - 1);
        const int y1 = min(y0 + 1, H - 1);
        const float wx = xs - (float)x0;
        const float wy = ys - (float)y0;
        const float w11 = wx * wy;
        const float w10 = wy - w11;
        const float w01 = wx - w11;
        const float w00 = 1.0f - wx - wy + w11;
        const int o00 = y0 * W + x0;
        const int o01 = y0 * W + x1;
        const int o10 = y1 * W + x0;
        const int o11 = y1 * W + x1;

        const float* f  = feat + ((size_t)b * C + (size_t)chunk * CH_PER_CHUNK) * HW;
        float*       op = roi + ((size_t)n * C + (size_t)chunk * CH_PER_CHUNK) * (OUTSZ * OUTSZ)
                              + (gy * OUTSZ + gx);
        const bool active = (gy < OUTSZ) && (gx < OUTSZ);

        #pragma unroll 4
        for (int cc = 0; cc < CH_PER_CHUNK; ++cc) {
            const float* fc = f + cc * HW;
            const float v = w00 * fc[o00] + w01 * fc[o01]
                          + w10 * fc[o10] + w11 * fc[o11];
            const float vr  = __shfl(v, lane + 1, 64);
            const float vd  = __shfl(v, lane + 8, 64);
            const float vdr = __shfl(v, lane + 9, 64);
            if (active) op[cc * (OUTSZ * OUTSZ)] = 0.25f * (v + vr + vd + vdr);
        }
    } else {
        // ---------------- tail path: mean + inner-crop, wave per (vf,c) -----
        const int tw = w - ROI_WAVES;

        // crop source indices for this lane's float4 (constant across tasks)
        int i0 = 0, i1 = 0, i2 = 0, i3 = 0;
        if (lane < 36) {
            const int o = lane * 4;
            i0 = ((o    ) / 12 + 1) * W + (o    ) % 12 + 1;
            i1 = ((o + 1) / 12 + 1) * W + (o + 1) % 12 + 1;
            i2 = ((o + 2) / 12 + 1) * W + (o + 2) % 12 + 1;
            i3 = ((o + 3) / 12 + 1) * W + (o + 3) % 12 + 1;
        }

        for (int task = tw; task < TAIL_TASKS; task += TAIL_WAVES) {
            const float* f = feat + (size_t)task * HW;

            // ---- mean of 196 floats: 49 lanes x float4 (784 B exactly) ----
            float4 v;
            if (lane < 49) v = ((const float4*)f)[lane];
            else           v = make_float4(0.f, 0.f, 0.f, 0.f);
            float s = v.x + v.y + v.z + v.w;
            #pragma unroll
            for (int off = 32; off; off >>= 1) s += __shfl_down(s, off, 64);
            if (lane == 0) s_node[task] = s * (1.0f / 196.0f);

            // ---- inner crop [1:13,1:13]: 36 lanes x float4 store ----------
            if (lane < 36) {
                float4 o4;
                o4.x = f[i0];  // L1 hits: region just read above
                o4.y = f[i1];
                o4.z = f[i2];
                o4.w = f[i3];
                ((float4*)(fake + (size_t)task * 144))[lane] = o4;
            }
        }
    }
}

extern "C" void kernel_launch(void* const* d_in, const int* in_sizes, int n_in,
                              void* d_out, int out_size, void* d_ws, size_t ws_size,
                              hipStream_t stream) {
    const float* feat  = (const float*)d_in[0];
    const float* boxes = (const float*)d_in[1];
    const int*   fidx  = (const int*)d_in[2];

    float* roi    = (float*)d_out;
    float* s_node = roi + ROI_ELEMS;
    float* fake   = s_node + SNODE_ELEMS;

    // 16384 waves total = 4096 blocks x 256 threads
    fused_kernel<<<TOTAL_WAVES / 4, 256, 0, stream>>>(feat, boxes, fidx,
                                                      roi, s_node, fake);
}